// Round 1
// baseline (1411.189 us; speedup 1.0000x reference)
//
#include <hip/hip_runtime.h>

// RelationProbe: out[r, row] = dot(z[row], W[r, pair_idx[row]]) + b[r, pair_idx[row]]
// B = 4194304, D = 64, N_REL = 4, N_PAIR = 6. Memory-bound on the 1 GiB z read.

#define D 64
#define N_REL 4
#define N_PAIR 6
#define N_HEAD (N_REL * N_PAIR)   // 24
// Head stride 68 floats (not 64): 68 mod 32 = 4, so distinct pair indices map to
// disjoint 4-bank spans for ds_read_b128 -> no LDS bank conflicts across lanes.
#define HEAD_STRIDE 68

__global__ __launch_bounds__(256) void relprobe_kernel(
    const float* __restrict__ z,
    const float* __restrict__ W,
    const float* __restrict__ bias,
    const int*   __restrict__ pair_idx,
    float*       __restrict__ out,
    int nrows)
{
    __shared__ float Wl[N_HEAD * HEAD_STRIDE];  // 24*68*4 = 6528 B
    __shared__ float bl[N_HEAD];

    const int tid = threadIdx.x;

    // Cooperative stage of W into padded LDS layout.
    for (int i = tid; i < N_HEAD * D; i += 256) {
        const int h = i >> 6;     // head index 0..23  (r*6 + p)
        const int k = i & 63;     // element within head
        Wl[h * HEAD_STRIDE + k] = W[i];
    }
    if (tid < N_HEAD) bl[tid] = bias[tid];
    __syncthreads();

    const int row = blockIdx.x * 256 + tid;
    if (row >= nrows) return;

    const int p = pair_idx[row];

    float acc0 = bl[0 * N_PAIR + p];
    float acc1 = bl[1 * N_PAIR + p];
    float acc2 = bl[2 * N_PAIR + p];
    float acc3 = bl[3 * N_PAIR + p];

    const float4* __restrict__ z4 =
        reinterpret_cast<const float4*>(z + (size_t)row * D);
    const float4* __restrict__ w0 =
        reinterpret_cast<const float4*>(&Wl[(0 * N_PAIR + p) * HEAD_STRIDE]);
    const float4* __restrict__ w1 =
        reinterpret_cast<const float4*>(&Wl[(1 * N_PAIR + p) * HEAD_STRIDE]);
    const float4* __restrict__ w2 =
        reinterpret_cast<const float4*>(&Wl[(2 * N_PAIR + p) * HEAD_STRIDE]);
    const float4* __restrict__ w3 =
        reinterpret_cast<const float4*>(&Wl[(3 * N_PAIR + p) * HEAD_STRIDE]);

#pragma unroll
    for (int k = 0; k < D / 4; ++k) {
        const float4 zv = z4[k];
        const float4 a0 = w0[k];
        const float4 a1 = w1[k];
        const float4 a2 = w2[k];
        const float4 a3 = w3[k];
        acc0 += zv.x * a0.x + zv.y * a0.y + zv.z * a0.z + zv.w * a0.w;
        acc1 += zv.x * a1.x + zv.y * a1.y + zv.z * a1.z + zv.w * a1.w;
        acc2 += zv.x * a2.x + zv.y * a2.y + zv.z * a2.z + zv.w * a2.w;
        acc3 += zv.x * a3.x + zv.y * a3.y + zv.z * a3.z + zv.w * a3.w;
    }

    const size_t Bsz = (size_t)nrows;
    out[0 * Bsz + row] = acc0;
    out[1 * Bsz + row] = acc1;
    out[2 * Bsz + row] = acc2;
    out[3 * Bsz + row] = acc3;
}

extern "C" void kernel_launch(void* const* d_in, const int* in_sizes, int n_in,
                              void* d_out, int out_size, void* d_ws, size_t ws_size,
                              hipStream_t stream) {
    const float* z        = (const float*)d_in[0];   // (B, 64) fp32
    const float* W        = (const float*)d_in[1];   // (4, 6, 64) fp32
    const float* bias     = (const float*)d_in[2];   // (4, 6) fp32
    const int*   pair_idx = (const int*)d_in[3];     // (B,) int
    float*       out      = (float*)d_out;           // (4, B) fp32

    const int nrows = in_sizes[3];                   // B
    const int grid  = (nrows + 255) / 256;
    relprobe_kernel<<<grid, 256, 0, stream>>>(z, W, bias, pair_idx, out, nrows);
}